// Round 1
// baseline (3538.214 us; speedup 1.0000x reference)
//
#include <hip/hip_runtime.h>
#include <math.h>

#define NN 100000
#define EE 500000
// D=H=128, ED=64, T=2, L=4

// ---------------- zero fill ----------------
__global__ void k_zero(float* __restrict__ p, size_t n) {
    size_t i = (size_t)blockIdx.x * blockDim.x + threadIdx.x;
    size_t stride = (size_t)gridDim.x * blockDim.x;
    for (; i < n; i += stride) p[i] = 0.0f;
}

// ---------------- prep: stacked edge-attention weight ----------------
// Wc[0:256]   = nl_att_W1[t][0:256]            (h_s, h_d parts)
// Wc[256:320] = nl_edge_W[t] @ nl_att_W1[t][256:384]   (folded he part, K=64)
// beff[j]     = nl_att_b1[t][j] + sum_m nl_edge_b[t][m]*W1[256+m][j]
__global__ void k_prep_edge(const float* __restrict__ W1, const float* __restrict__ We,
                            const float* __restrict__ be, const float* __restrict__ b1,
                            float* __restrict__ Wc, float* __restrict__ beff) {
    int b = blockIdx.x, tid = threadIdx.x;
    if (b < 256) {
        Wc[b * 128 + tid] = W1[b * 128 + tid];
    } else if (b < 320) {
        int k = b - 256;
        float a = 0.0f;
        for (int m = 0; m < 128; m++) a += We[k * 128 + m] * W1[(256 + m) * 128 + tid];
        Wc[b * 128 + tid] = a;
    } else {
        float a = b1[tid];
        for (int m = 0; m < 128; m++) a += be[m] * W1[(256 + m) * 128 + tid];
        beff[tid] = a;
    }
}

// ---------------- plain GEMM: C[M,128] = A[M,128] @ W[128,128] (+bias) ----------------
__global__ __launch_bounds__(256) void k_gemm_plain(const float* __restrict__ A,
                                                    const float* __restrict__ W,
                                                    const float* __restrict__ bias,
                                                    float* __restrict__ C) {
    __shared__ __align__(16) float T[16][128];
    int tid = threadIdx.x;
    long row0 = (long)blockIdx.x * 16;
#pragma unroll
    for (int i = 0; i < 8; i++) {
        int idx = tid + i * 256;
        int r = idx >> 7, c = idx & 127;
        T[r][c] = A[(row0 + r) * 128 + c];
    }
    __syncthreads();
    int j = tid & 127, half = tid >> 7;
    float acc[8] = {0, 0, 0, 0, 0, 0, 0, 0};
    for (int k4 = 0; k4 < 32; k4++) {
        float w0 = W[(k4 * 4 + 0) * 128 + j];
        float w1 = W[(k4 * 4 + 1) * 128 + j];
        float w2 = W[(k4 * 4 + 2) * 128 + j];
        float w3 = W[(k4 * 4 + 3) * 128 + j];
#pragma unroll
        for (int r = 0; r < 8; r++) {
            float4 c4 = *reinterpret_cast<const float4*>(&T[half * 8 + r][k4 * 4]);
            acc[r] += c4.x * w0 + c4.y * w1 + c4.z * w2 + c4.w * w3;
        }
    }
    float bj = bias ? bias[j] : 0.0f;
#pragma unroll
    for (int r = 0; r < 8; r++) {
        int rr = half * 8 + r;
        C[(row0 + rr) * 128 + j] = acc[r] + bj;
    }
}

// ---------------- GEMM + LayerNorm + ReLU ----------------
__global__ __launch_bounds__(256) void k_gemm_ln(const float* __restrict__ A,
                                                 const float* __restrict__ W,
                                                 const float* __restrict__ bias,
                                                 const float* __restrict__ g,
                                                 const float* __restrict__ bln,
                                                 float* __restrict__ C) {
    __shared__ __align__(16) float T[16][128];
    __shared__ float mu[16], rs[16];
    int tid = threadIdx.x;
    long row0 = (long)blockIdx.x * 16;
#pragma unroll
    for (int i = 0; i < 8; i++) {
        int idx = tid + i * 256;
        int r = idx >> 7, c = idx & 127;
        T[r][c] = A[(row0 + r) * 128 + c];
    }
    __syncthreads();
    int j = tid & 127, half = tid >> 7;
    float acc[8] = {0, 0, 0, 0, 0, 0, 0, 0};
    for (int k4 = 0; k4 < 32; k4++) {
        float w0 = W[(k4 * 4 + 0) * 128 + j];
        float w1 = W[(k4 * 4 + 1) * 128 + j];
        float w2 = W[(k4 * 4 + 2) * 128 + j];
        float w3 = W[(k4 * 4 + 3) * 128 + j];
#pragma unroll
        for (int r = 0; r < 8; r++) {
            float4 c4 = *reinterpret_cast<const float4*>(&T[half * 8 + r][k4 * 4]);
            acc[r] += c4.x * w0 + c4.y * w1 + c4.z * w2 + c4.w * w3;
        }
    }
    __syncthreads();
    float bj = bias[j];
#pragma unroll
    for (int r = 0; r < 8; r++) T[half * 8 + r][j] = acc[r] + bj;
    __syncthreads();
    int gr = tid >> 4, lane = tid & 15;
    float sm = 0.0f, sq = 0.0f;
#pragma unroll
    for (int i = 0; i < 8; i++) {
        float v = T[gr][lane + 16 * i];
        sm += v; sq += v * v;
    }
#pragma unroll
    for (int m = 1; m < 16; m <<= 1) { sm += __shfl_xor(sm, m); sq += __shfl_xor(sq, m); }
    if (lane == 0) {
        float mean = sm * (1.0f / 128.0f);
        float var = sq * (1.0f / 128.0f) - mean * mean;
        mu[gr] = mean;
        rs[gr] = rsqrtf(var + 1e-5f);
    }
    __syncthreads();
    float gj = g[j], bb = bln[j];
#pragma unroll
    for (int r = 0; r < 8; r++) {
        int rr = half * 8 + r;
        float v = (T[rr][j] - mu[rr]) * rs[rr] * gj + bb;
        C[(row0 + rr) * 128 + j] = fmaxf(v, 0.0f);
    }
}

// ---------------- fusion-weighted GEMM + LN + ReLU (P6) ----------------
__global__ __launch_bounds__(256) void k_fuse_gemm_ln(const float* __restrict__ emb0,
                                                      const float* __restrict__ emb1,
                                                      const float* __restrict__ scores,
                                                      const float* __restrict__ W,
                                                      const float* __restrict__ bias,
                                                      const float* __restrict__ g,
                                                      const float* __restrict__ bln,
                                                      float* __restrict__ C) {
    __shared__ __align__(16) float T[16][128];
    __shared__ float mu[16], rs[16];
    int tid = threadIdx.x;
    long row0 = (long)blockIdx.x * 16;
#pragma unroll
    for (int i = 0; i < 8; i++) {
        int idx = tid + i * 256;
        int r = idx >> 7, c = idx & 127;
        long row = row0 + r;
        float s0 = scores[row * 2 + 0], s1 = scores[row * 2 + 1];
        float mx = fmaxf(s0, s1);
        float e0 = expf(s0 - mx), e1 = expf(s1 - mx);
        float inv = 1.0f / (e0 + e1);
        T[r][c] = (e0 * emb0[row * 128 + c] + e1 * emb1[row * 128 + c]) * inv;
    }
    __syncthreads();
    int j = tid & 127, half = tid >> 7;
    float acc[8] = {0, 0, 0, 0, 0, 0, 0, 0};
    for (int k4 = 0; k4 < 32; k4++) {
        float w0 = W[(k4 * 4 + 0) * 128 + j];
        float w1 = W[(k4 * 4 + 1) * 128 + j];
        float w2 = W[(k4 * 4 + 2) * 128 + j];
        float w3 = W[(k4 * 4 + 3) * 128 + j];
#pragma unroll
        for (int r = 0; r < 8; r++) {
            float4 c4 = *reinterpret_cast<const float4*>(&T[half * 8 + r][k4 * 4]);
            acc[r] += c4.x * w0 + c4.y * w1 + c4.z * w2 + c4.w * w3;
        }
    }
    __syncthreads();
    float bj = bias[j];
#pragma unroll
    for (int r = 0; r < 8; r++) T[half * 8 + r][j] = acc[r] + bj;
    __syncthreads();
    int gr = tid >> 4, lane = tid & 15;
    float sm = 0.0f, sq = 0.0f;
#pragma unroll
    for (int i = 0; i < 8; i++) {
        float v = T[gr][lane + 16 * i];
        sm += v; sq += v * v;
    }
#pragma unroll
    for (int m = 1; m < 16; m <<= 1) { sm += __shfl_xor(sm, m); sq += __shfl_xor(sq, m); }
    if (lane == 0) {
        float mean = sm * (1.0f / 128.0f);
        float var = sq * (1.0f / 128.0f) - mean * mean;
        mu[gr] = mean;
        rs[gr] = rsqrtf(var + 1e-5f);
    }
    __syncthreads();
    float gj = g[j], bb = bln[j];
#pragma unroll
    for (int r = 0; r < 8; r++) {
        int rr = half * 8 + r;
        float v = (T[rr][j] - mu[rr]) * rs[rr] * gj + bb;
        C[(row0 + rr) * 128 + j] = fmaxf(v, 0.0f);
    }
}

// ---------------- per-row level-selected GEMM (P7: hf) ----------------
__global__ __launch_bounds__(256) void k_gemm_level(const float* __restrict__ A,
                                                    const int* __restrict__ levels,
                                                    const float* __restrict__ Wl,
                                                    const float* __restrict__ bl,
                                                    float* __restrict__ C) {
    __shared__ __align__(16) float T[16][128];
    __shared__ int lv[16];
    int tid = threadIdx.x;
    long row0 = (long)blockIdx.x * 16;
#pragma unroll
    for (int i = 0; i < 8; i++) {
        int idx = tid + i * 256;
        int r = idx >> 7, c = idx & 127;
        T[r][c] = A[(row0 + r) * 128 + c];
    }
    if (tid < 16) lv[tid] = levels[row0 + tid];
    __syncthreads();
    int j = tid & 127, half = tid >> 7;
#pragma unroll
    for (int r = 0; r < 8; r++) {
        int rr = half * 8 + r;
        const float* Wr = Wl + (size_t)lv[rr] * 16384;
        float a = 0.0f;
        for (int k4 = 0; k4 < 32; k4++) {
            float4 c4 = *reinterpret_cast<const float4*>(&T[rr][k4 * 4]);
            a += c4.x * Wr[(k4 * 4 + 0) * 128 + j];
            a += c4.y * Wr[(k4 * 4 + 1) * 128 + j];
            a += c4.z * Wr[(k4 * 4 + 2) * 128 + j];
            a += c4.w * Wr[(k4 * 4 + 3) * 128 + j];
        }
        C[(row0 + rr) * 128 + j] = a + bl[(size_t)lv[rr] * 128 + j];
    }
}

// ---------------- edge attention scores (P2), 16 edges/block ----------------
__global__ __launch_bounds__(256) void k_edge_scores(const float* __restrict__ h,
                                                     const float* __restrict__ ef,
                                                     const int* __restrict__ eis,
                                                     const int* __restrict__ eid,
                                                     const float* __restrict__ Wc,
                                                     const float* __restrict__ beff,
                                                     const float* __restrict__ W2,
                                                     const float* __restrict__ b2p,
                                                     float* __restrict__ ebuf,
                                                     float* __restrict__ z) {
    __shared__ __align__(16) float cat[16][320];
    __shared__ int sidx[16];
    __shared__ float part[4][8];
    int tid = threadIdx.x;
    long e0 = (long)blockIdx.x * 16;
    // stage h[s], h[d]
    int kk = tid & 127;
    for (int i = 0; i < 16; i++) {
        long e = e0 + i;
        int s = eis[e];
        int dd = eid[e];
        const float* src = (tid < 128) ? (h + (size_t)s * 128) : (h + (size_t)dd * 128);
        cat[i][(tid < 128 ? 0 : 128) + kk] = src[kk];
    }
    // stage edge features (64 each), 4 edges per pass
    for (int it = 0; it < 4; it++) {
        int i = it * 4 + (tid >> 6);
        int k = tid & 63;
        cat[i][256 + k] = ef[(size_t)(e0 + i) * 64 + k];
    }
    if (tid < 16) sidx[tid] = eis[e0 + tid];
    __syncthreads();
    int j = tid & 127, half = tid >> 7;
    float acc[8] = {0, 0, 0, 0, 0, 0, 0, 0};
    for (int k4 = 0; k4 < 80; k4++) {
        float w0 = Wc[(k4 * 4 + 0) * 128 + j];
        float w1 = Wc[(k4 * 4 + 1) * 128 + j];
        float w2 = Wc[(k4 * 4 + 2) * 128 + j];
        float w3 = Wc[(k4 * 4 + 3) * 128 + j];
#pragma unroll
        for (int r = 0; r < 8; r++) {
            float4 c4 = *reinterpret_cast<const float4*>(&cat[half * 8 + r][k4 * 4]);
            acc[r] += c4.x * w0 + c4.y * w1 + c4.z * w2 + c4.w * w3;
        }
    }
    float bj = beff[j];
    float w2j = W2[j];
#pragma unroll
    for (int r = 0; r < 8; r++) {
        float v = tanhf(acc[r] + bj) * w2j;
#pragma unroll
        for (int o = 32; o > 0; o >>= 1) v += __shfl_down(v, o);
        if ((tid & 63) == 0) part[tid >> 6][r] = v;
    }
    __syncthreads();
    if (tid < 16) {
        int hh = tid >> 3, r = tid & 7;
        float a = part[hh * 2][r] + part[hh * 2 + 1][r] + b2p[0];
        float ev = expf(a);
        ebuf[e0 + tid] = ev;
        atomicAdd(&z[sidx[tid]], ev);
    }
}

// ---------------- aggregation (P3): agg[s] += alpha * h[d] ----------------
__global__ __launch_bounds__(256) void k_agg(const float* __restrict__ h,
                                             const float* __restrict__ ebuf,
                                             const float* __restrict__ z,
                                             const int* __restrict__ eis,
                                             const int* __restrict__ eid,
                                             float* __restrict__ agg) {
    int tid = threadIdx.x;
    long e = (long)blockIdx.x * 2 + (tid >> 7);
    int j = tid & 127;
    int s = eis[e], dd = eid[e];
    float alpha = ebuf[e] / (z[s] + 1e-16f);
    atomicAdd(&agg[(size_t)s * 128 + j], alpha * h[(size_t)dd * 128 + j]);
}

// ---------------- per-node relation score (P5) ----------------
__global__ __launch_bounds__(256) void k_score(const float* __restrict__ emb,
                                               const float* __restrict__ W1,
                                               const float* __restrict__ b1,
                                               const float* __restrict__ W2,
                                               const float* __restrict__ b2p,
                                               float* __restrict__ scores, int t) {
    __shared__ __align__(16) float T[16][128];
    __shared__ float part[4][8];
    int tid = threadIdx.x;
    long row0 = (long)blockIdx.x * 16;
#pragma unroll
    for (int i = 0; i < 8; i++) {
        int idx = tid + i * 256;
        int r = idx >> 7, c = idx & 127;
        T[r][c] = emb[(row0 + r) * 128 + c];
    }
    __syncthreads();
    int j = tid & 127, half = tid >> 7;
    float acc[8] = {0, 0, 0, 0, 0, 0, 0, 0};
    for (int k4 = 0; k4 < 32; k4++) {
        float w0 = W1[(k4 * 4 + 0) * 128 + j];
        float w1 = W1[(k4 * 4 + 1) * 128 + j];
        float w2 = W1[(k4 * 4 + 2) * 128 + j];
        float w3 = W1[(k4 * 4 + 3) * 128 + j];
#pragma unroll
        for (int r = 0; r < 8; r++) {
            float4 c4 = *reinterpret_cast<const float4*>(&T[half * 8 + r][k4 * 4]);
            acc[r] += c4.x * w0 + c4.y * w1 + c4.z * w2 + c4.w * w3;
        }
    }
    float bj = b1[j], w2j = W2[j];
#pragma unroll
    for (int r = 0; r < 8; r++) {
        float v = tanhf(acc[r] + bj) * w2j;
#pragma unroll
        for (int o = 32; o > 0; o >>= 1) v += __shfl_down(v, o);
        if ((tid & 63) == 0) part[tid >> 6][r] = v;
    }
    __syncthreads();
    if (tid < 16) {
        int hh = tid >> 3, r = tid & 7;
        float a = part[hh * 2][r] + part[hh * 2 + 1][r] + b2p[0];
        scores[(row0 + tid) * 2 + t] = a;
    }
}

// ---------------- level mean accumulate (P7b) ----------------
__global__ __launch_bounds__(128) void k_lmean_acc(const float* __restrict__ hf,
                                                   const int* __restrict__ lev,
                                                   float* __restrict__ lsum,
                                                   float* __restrict__ cnt) {
    __shared__ float ls[4][128];
    __shared__ float lc[4];
    int tid = threadIdx.x;
#pragma unroll
    for (int l = 0; l < 4; l++) ls[l][tid] = 0.0f;
    if (tid < 4) lc[tid] = 0.0f;
    __syncthreads();
    long row0 = (long)blockIdx.x * 32;
    for (int r = 0; r < 32; r++) {
        long row = row0 + r;
        int l = lev[row];
        ls[l][tid] += hf[row * 128 + tid];
        if (tid == 0) lc[l] += 1.0f;
    }
    __syncthreads();
#pragma unroll
    for (int l = 0; l < 4; l++) atomicAdd(&lsum[l * 128 + tid], ls[l][tid]);
    if (tid < 4) atomicAdd(&cnt[tid], lc[tid]);
}

// ---------------- level mean finalize + lmean@W1b + b1 (P9) ----------------
__global__ void k_lmean_fin(const float* __restrict__ lsum, const float* __restrict__ cnt,
                            const float* __restrict__ W1b, const float* __restrict__ b1,
                            float* __restrict__ lmean, float* __restrict__ lmw) {
    __shared__ float lml[128];
    int l = blockIdx.x, tid = threadIdx.x;
    float c = cnt[l];
    c = c < 1.0f ? 1.0f : c;
    float v = lsum[l * 128 + tid] / c;
    lmean[l * 128 + tid] = v;
    lml[tid] = v;
    __syncthreads();
    float a = b1[tid];
    for (int k = 0; k < 128; k++) a += lml[k] * W1b[k * 128 + tid];
    lmw[l * 128 + tid] = a;
}

// ---------------- hierarchical attention (P10a): enhanced rows ----------------
__global__ __launch_bounds__(256) void k_hier(const float* __restrict__ hfa,
                                              const float* __restrict__ lmw,
                                              const float* __restrict__ lmean,
                                              const float* __restrict__ W2,
                                              const float* __restrict__ b2p,
                                              float* __restrict__ enh) {
    __shared__ __align__(16) float T[16][128];
    __shared__ float lm[4][128];
    __shared__ float part[4][8][4];
    __shared__ float aw[16][4];
    int tid = threadIdx.x;
    long row0 = (long)blockIdx.x * 16;
#pragma unroll
    for (int i = 0; i < 8; i++) {
        int idx = tid + i * 256;
        T[idx >> 7][idx & 127] = hfa[(row0 + (idx >> 7)) * 128 + (idx & 127)];
    }
    for (int idx = tid; idx < 512; idx += 256) lm[idx >> 7][idx & 127] = lmean[idx];
    __syncthreads();
    int j = tid & 127, half = tid >> 7;
    float w2j = W2[j];
    float lw[4];
#pragma unroll
    for (int l = 0; l < 4; l++) lw[l] = lmw[l * 128 + j];
#pragma unroll
    for (int r = 0; r < 8; r++) {
        int rr = half * 8 + r;
        float hv = T[rr][j];
#pragma unroll
        for (int l = 0; l < 4; l++) {
            float v = tanhf(hv + lw[l]) * w2j;
#pragma unroll
            for (int o = 32; o > 0; o >>= 1) v += __shfl_down(v, o);
            if ((tid & 63) == 0) part[tid >> 6][r][l] = v;
        }
    }
    __syncthreads();
    if (tid < 16) {
        int hh = tid >> 3, r = tid & 7;
        float b2 = b2p[0];
        float sc[4];
        float mx = -1e30f;
#pragma unroll
        for (int l = 0; l < 4; l++) {
            sc[l] = part[hh * 2][r][l] + part[hh * 2 + 1][r][l] + b2;
            mx = fmaxf(mx, sc[l]);
        }
        float s = 0.0f;
#pragma unroll
        for (int l = 0; l < 4; l++) { sc[l] = expf(sc[l] - mx); s += sc[l]; }
        float inv = 1.0f / s;
#pragma unroll
        for (int l = 0; l < 4; l++) aw[tid][l] = sc[l] * inv;
    }
    __syncthreads();
#pragma unroll
    for (int r = 0; r < 8; r++) {
        int rr = half * 8 + r;
        float e = 0.0f;
#pragma unroll
        for (int l = 0; l < 4; l++) e += aw[rr][l] * lm[l][j];
        enh[(row0 + rr) * 128 + j] = e;
    }
}

extern "C" void kernel_launch(void* const* d_in, const int* in_sizes, int n_in,
                              void* d_out, int out_size, void* d_ws, size_t ws_size,
                              hipStream_t stream) {
    const float* nf  = (const float*)d_in[0];
    const float* ef  = (const float*)d_in[1];
    const int*   lev = (const int*)d_in[2];
    const int*   ei  = (const int*)d_in[3];
    const float* nlW = (const float*)d_in[4];
    const float* nlb = (const float*)d_in[5];
    const float* neW = (const float*)d_in[6];
    const float* neb = (const float*)d_in[7];
    const float* aW1 = (const float*)d_in[8];
    const float* ab1 = (const float*)d_in[9];
    const float* aW2 = (const float*)d_in[10];
    const float* ab2 = (const float*)d_in[11];
    const float* oW  = (const float*)d_in[12];
    const float* ob  = (const float*)d_in[13];
    const float* lng = (const float*)d_in[14];
    const float* lnb = (const float*)d_in[15];
    const float* eW1 = (const float*)d_in[16];
    const float* eb1 = (const float*)d_in[17];
    const float* eW2 = (const float*)d_in[18];
    const float* eb2 = (const float*)d_in[19];
    const float* eoW = (const float*)d_in[20];
    const float* eob = (const float*)d_in[21];
    const float* elg = (const float*)d_in[22];
    const float* elb = (const float*)d_in[23];
    const float* hpW = (const float*)d_in[24];
    const float* hpb = (const float*)d_in[25];
    const float* hW1 = (const float*)d_in[26];
    const float* hb1 = (const float*)d_in[27];
    const float* hW2 = (const float*)d_in[28];
    const float* hb2 = (const float*)d_in[29];
    const float* hoW = (const float*)d_in[30];
    const float* hob = (const float*)d_in[31];
    const float* hlg = (const float*)d_in[32];
    const float* hlb = (const float*)d_in[33];

    float* ws = (float*)d_ws;
    size_t NH = (size_t)NN * 128;
    float* h      = ws;
    float* ebuf   = h + NH;
    float* z      = ebuf + EE;
    float* agg    = z + NN;
    float* emb0   = agg + NH;
    float* emb1   = emb0 + NH;
    float* scores = emb1 + NH;
    float* Wc     = scores + (size_t)NN * 2;
    float* beff   = Wc + 320 * 128;
    float* lsum   = beff + 128;
    float* cnt    = lsum + 512;
    float* lmean  = cnt + 4;
    float* lmw    = lmean + 512;
    // aliases (lifetime-disjoint)
    float* fused = h;
    float* hfbuf = agg;
    float* hfa   = emb0;
    float* enh   = emb1;
    float* out   = (float*)d_out;

    for (int t = 0; t < 2; t++) {
        k_prep_edge<<<321, 128, 0, stream>>>(aW1 + (size_t)t * 384 * 128,
                                             neW + (size_t)t * 64 * 128,
                                             neb + t * 128, ab1 + t * 128, Wc, beff);
        k_gemm_plain<<<NN / 16, 256, 0, stream>>>(nf, nlW + (size_t)t * 128 * 128,
                                                  nlb + t * 128, h);
        k_zero<<<256, 256, 0, stream>>>(z, (size_t)NN);
        const int* eis = ei + (size_t)t * 2 * EE;
        const int* eid = eis + EE;
        k_edge_scores<<<EE / 16, 256, 0, stream>>>(h, ef + (size_t)t * EE * 64, eis, eid,
                                                   Wc, beff, aW2 + t * 128, ab2 + t,
                                                   ebuf, z);
        k_zero<<<2048, 256, 0, stream>>>(agg, NH);
        k_agg<<<EE / 2, 256, 0, stream>>>(h, ebuf, z, eis, eid, agg);
        float* embt = (t == 0) ? emb0 : emb1;
        k_gemm_ln<<<NN / 16, 256, 0, stream>>>(agg, oW + (size_t)t * 128 * 128,
                                               ob + t * 128, lng + t * 128, lnb + t * 128,
                                               embt);
        k_score<<<NN / 16, 256, 0, stream>>>(embt, eW1 + (size_t)t * 128 * 128,
                                             eb1 + t * 128, eW2 + t * 128, eb2 + t,
                                             scores, t);
    }
    k_fuse_gemm_ln<<<NN / 16, 256, 0, stream>>>(emb0, emb1, scores, eoW, eob, elg, elb,
                                                fused);
    k_gemm_level<<<NN / 16, 256, 0, stream>>>(fused, lev, hpW, hpb, hfbuf);
    k_zero<<<2, 256, 0, stream>>>(lsum, (size_t)516);
    k_lmean_acc<<<NN / 32, 128, 0, stream>>>(hfbuf, lev, lsum, cnt);
    k_gemm_plain<<<NN / 16, 256, 0, stream>>>(hfbuf, hW1, nullptr, hfa);
    k_lmean_fin<<<4, 128, 0, stream>>>(lsum, cnt, hW1 + 128 * 128, hb1, lmean, lmw);
    k_hier<<<NN / 16, 256, 0, stream>>>(hfa, lmw, lmean, hW2, hb2, enh);
    k_gemm_ln<<<NN / 16, 256, 0, stream>>>(enh, hoW, hob, hlg, hlb, out);
}

// Round 2
// 2052.819 us; speedup vs baseline: 1.7236x; 1.7236x over previous
//
#include <hip/hip_runtime.h>
#include <math.h>

#define NN 100000
#define EE 500000
// D=H=128, ED=64, T=2, L=4

typedef __attribute__((ext_vector_type(8))) short bf16x8;
typedef __attribute__((ext_vector_type(4))) float f32x4;

__device__ inline short f2bf(float x) {
    union { float f; unsigned u; } v; v.f = x;
    unsigned r = v.u + 0x7FFF + ((v.u >> 16) & 1);
    return (short)(r >> 16);
}

// ---------------- zero fill ----------------
__global__ void k_zero(float* __restrict__ p, size_t n) {
    size_t i = (size_t)blockIdx.x * blockDim.x + threadIdx.x;
    size_t stride = (size_t)gridDim.x * blockDim.x;
    for (; i < n; i += stride) p[i] = 0.0f;
}

// ---------------- h -> bf16 ----------------
__global__ void k_h2bf(const float* __restrict__ h, unsigned short* __restrict__ hbf,
                       size_t n) {
    size_t i = ((size_t)blockIdx.x * blockDim.x + threadIdx.x) * 4;
    size_t stride = (size_t)gridDim.x * blockDim.x * 4;
    for (; i < n; i += stride) {
        float4 f = *(const float4*)(h + i);
        ushort4 u;
        u.x = (unsigned short)f2bf(f.x);
        u.y = (unsigned short)f2bf(f.y);
        u.z = (unsigned short)f2bf(f.z);
        u.w = (unsigned short)f2bf(f.w);
        *(ushort4*)(hbf + i) = u;
    }
}

// ---------------- prep: WcT bf16 [128][320] + beff ----------------
// Wc[0:256][j]   = nl_att_W1[t][0:256][j]
// Wc[256+ke][j]  = sum_m nl_edge_W[t][ke][m] * W1[256+m][j]
// beff[j]        = b1[j] + sum_m be[m]*W1[256+m][j]
// WcT[j][k] = bf16(Wc[k][j])
__global__ void k_prep_edge2(const float* __restrict__ W1, const float* __restrict__ We,
                             const float* __restrict__ be, const float* __restrict__ b1,
                             unsigned short* __restrict__ WcT, float* __restrict__ beff) {
    int b = blockIdx.x, tid = threadIdx.x;
    if (b < 128) {
        int j = b, k = tid;  // 320 threads
        float a;
        if (k < 256) {
            a = W1[k * 128 + j];
        } else {
            a = 0.0f;
            int ke = k - 256;
            for (int m = 0; m < 128; m++) a = fmaf(We[ke * 128 + m], W1[(256 + m) * 128 + j], a);
        }
        WcT[j * 320 + k] = (unsigned short)f2bf(a);
    } else if (tid < 128) {
        float a = b1[tid];
        for (int m = 0; m < 128; m++) a = fmaf(be[m], W1[(256 + m) * 128 + tid], a);
        beff[tid] = a;
    }
}

// ---------------- plain GEMM: C[M,128] = A[M,128] @ W[128,128] (+bias) ----------------
__global__ __launch_bounds__(256) void k_gemm_plain(const float* __restrict__ A,
                                                    const float* __restrict__ W,
                                                    const float* __restrict__ bias,
                                                    float* __restrict__ C) {
    __shared__ __align__(16) float T[16][128];
    int tid = threadIdx.x;
    long row0 = (long)blockIdx.x * 16;
#pragma unroll
    for (int i = 0; i < 8; i++) {
        int idx = tid + i * 256;
        int r = idx >> 7, c = idx & 127;
        T[r][c] = A[(row0 + r) * 128 + c];
    }
    __syncthreads();
    int j = tid & 127, half = tid >> 7;
    float acc[8] = {0, 0, 0, 0, 0, 0, 0, 0};
    for (int k4 = 0; k4 < 32; k4++) {
        float w0 = W[(k4 * 4 + 0) * 128 + j];
        float w1 = W[(k4 * 4 + 1) * 128 + j];
        float w2 = W[(k4 * 4 + 2) * 128 + j];
        float w3 = W[(k4 * 4 + 3) * 128 + j];
#pragma unroll
        for (int r = 0; r < 8; r++) {
            float4 c4 = *reinterpret_cast<const float4*>(&T[half * 8 + r][k4 * 4]);
            acc[r] = fmaf(c4.x, w0, acc[r]);
            acc[r] = fmaf(c4.y, w1, acc[r]);
            acc[r] = fmaf(c4.z, w2, acc[r]);
            acc[r] = fmaf(c4.w, w3, acc[r]);
        }
    }
    float bj = bias ? bias[j] : 0.0f;
#pragma unroll
    for (int r = 0; r < 8; r++) {
        int rr = half * 8 + r;
        C[(row0 + rr) * 128 + j] = acc[r] + bj;
    }
}

// ---------------- GEMM + LayerNorm + ReLU ----------------
__global__ __launch_bounds__(256) void k_gemm_ln(const float* __restrict__ A,
                                                 const float* __restrict__ W,
                                                 const float* __restrict__ bias,
                                                 const float* __restrict__ g,
                                                 const float* __restrict__ bln,
                                                 float* __restrict__ C) {
    __shared__ __align__(16) float T[16][128];
    __shared__ float mu[16], rs[16];
    int tid = threadIdx.x;
    long row0 = (long)blockIdx.x * 16;
#pragma unroll
    for (int i = 0; i < 8; i++) {
        int idx = tid + i * 256;
        int r = idx >> 7, c = idx & 127;
        T[r][c] = A[(row0 + r) * 128 + c];
    }
    __syncthreads();
    int j = tid & 127, half = tid >> 7;
    float acc[8] = {0, 0, 0, 0, 0, 0, 0, 0};
    for (int k4 = 0; k4 < 32; k4++) {
        float w0 = W[(k4 * 4 + 0) * 128 + j];
        float w1 = W[(k4 * 4 + 1) * 128 + j];
        float w2 = W[(k4 * 4 + 2) * 128 + j];
        float w3 = W[(k4 * 4 + 3) * 128 + j];
#pragma unroll
        for (int r = 0; r < 8; r++) {
            float4 c4 = *reinterpret_cast<const float4*>(&T[half * 8 + r][k4 * 4]);
            acc[r] = fmaf(c4.x, w0, acc[r]);
            acc[r] = fmaf(c4.y, w1, acc[r]);
            acc[r] = fmaf(c4.z, w2, acc[r]);
            acc[r] = fmaf(c4.w, w3, acc[r]);
        }
    }
    __syncthreads();
    float bj = bias[j];
#pragma unroll
    for (int r = 0; r < 8; r++) T[half * 8 + r][j] = acc[r] + bj;
    __syncthreads();
    int gr = tid >> 4, lane = tid & 15;
    float sm = 0.0f, sq = 0.0f;
#pragma unroll
    for (int i = 0; i < 8; i++) {
        float v = T[gr][lane + 16 * i];
        sm += v; sq += v * v;
    }
#pragma unroll
    for (int m = 1; m < 16; m <<= 1) { sm += __shfl_xor(sm, m); sq += __shfl_xor(sq, m); }
    if (lane == 0) {
        float mean = sm * (1.0f / 128.0f);
        float var = sq * (1.0f / 128.0f) - mean * mean;
        mu[gr] = mean;
        rs[gr] = rsqrtf(var + 1e-5f);
    }
    __syncthreads();
    float gj = g[j], bb = bln[j];
#pragma unroll
    for (int r = 0; r < 8; r++) {
        int rr = half * 8 + r;
        float v = (T[rr][j] - mu[rr]) * rs[rr] * gj + bb;
        C[(row0 + rr) * 128 + j] = fmaxf(v, 0.0f);
    }
}

// ---------------- fusion-weighted GEMM + LN + ReLU ----------------
__global__ __launch_bounds__(256) void k_fuse_gemm_ln(const float* __restrict__ emb0,
                                                      const float* __restrict__ emb1,
                                                      const float* __restrict__ scores,
                                                      const float* __restrict__ W,
                                                      const float* __restrict__ bias,
                                                      const float* __restrict__ g,
                                                      const float* __restrict__ bln,
                                                      float* __restrict__ C) {
    __shared__ __align__(16) float T[16][128];
    __shared__ float mu[16], rs[16];
    int tid = threadIdx.x;
    long row0 = (long)blockIdx.x * 16;
#pragma unroll
    for (int i = 0; i < 8; i++) {
        int idx = tid + i * 256;
        int r = idx >> 7, c = idx & 127;
        long row = row0 + r;
        float s0 = scores[row * 2 + 0], s1 = scores[row * 2 + 1];
        float mx = fmaxf(s0, s1);
        float e0 = expf(s0 - mx), e1 = expf(s1 - mx);
        float inv = 1.0f / (e0 + e1);
        T[r][c] = (e0 * emb0[row * 128 + c] + e1 * emb1[row * 128 + c]) * inv;
    }
    __syncthreads();
    int j = tid & 127, half = tid >> 7;
    float acc[8] = {0, 0, 0, 0, 0, 0, 0, 0};
    for (int k4 = 0; k4 < 32; k4++) {
        float w0 = W[(k4 * 4 + 0) * 128 + j];
        float w1 = W[(k4 * 4 + 1) * 128 + j];
        float w2 = W[(k4 * 4 + 2) * 128 + j];
        float w3 = W[(k4 * 4 + 3) * 128 + j];
#pragma unroll
        for (int r = 0; r < 8; r++) {
            float4 c4 = *reinterpret_cast<const float4*>(&T[half * 8 + r][k4 * 4]);
            acc[r] = fmaf(c4.x, w0, acc[r]);
            acc[r] = fmaf(c4.y, w1, acc[r]);
            acc[r] = fmaf(c4.z, w2, acc[r]);
            acc[r] = fmaf(c4.w, w3, acc[r]);
        }
    }
    __syncthreads();
    float bj = bias[j];
#pragma unroll
    for (int r = 0; r < 8; r++) T[half * 8 + r][j] = acc[r] + bj;
    __syncthreads();
    int gr = tid >> 4, lane = tid & 15;
    float sm = 0.0f, sq = 0.0f;
#pragma unroll
    for (int i = 0; i < 8; i++) {
        float v = T[gr][lane + 16 * i];
        sm += v; sq += v * v;
    }
#pragma unroll
    for (int m = 1; m < 16; m <<= 1) { sm += __shfl_xor(sm, m); sq += __shfl_xor(sq, m); }
    if (lane == 0) {
        float mean = sm * (1.0f / 128.0f);
        float var = sq * (1.0f / 128.0f) - mean * mean;
        mu[gr] = mean;
        rs[gr] = rsqrtf(var + 1e-5f);
    }
    __syncthreads();
    float gj = g[j], bb = bln[j];
#pragma unroll
    for (int r = 0; r < 8; r++) {
        int rr = half * 8 + r;
        float v = (T[rr][j] - mu[rr]) * rs[rr] * gj + bb;
        C[(row0 + rr) * 128 + j] = fmaxf(v, 0.0f);
    }
}

// ---------------- per-row level-selected GEMM ----------------
__global__ __launch_bounds__(256) void k_gemm_level(const float* __restrict__ A,
                                                    const int* __restrict__ levels,
                                                    const float* __restrict__ Wl,
                                                    const float* __restrict__ bl,
                                                    float* __restrict__ C) {
    __shared__ __align__(16) float T[16][128];
    __shared__ int lv[16];
    int tid = threadIdx.x;
    long row0 = (long)blockIdx.x * 16;
#pragma unroll
    for (int i = 0; i < 8; i++) {
        int idx = tid + i * 256;
        int r = idx >> 7, c = idx & 127;
        T[r][c] = A[(row0 + r) * 128 + c];
    }
    if (tid < 16) lv[tid] = levels[row0 + tid];
    __syncthreads();
    int j = tid & 127, half = tid >> 7;
#pragma unroll
    for (int r = 0; r < 8; r++) {
        int rr = half * 8 + r;
        const float* Wr = Wl + (size_t)lv[rr] * 16384;
        float a = 0.0f;
        for (int k4 = 0; k4 < 32; k4++) {
            float4 c4 = *reinterpret_cast<const float4*>(&T[rr][k4 * 4]);
            a = fmaf(c4.x, Wr[(k4 * 4 + 0) * 128 + j], a);
            a = fmaf(c4.y, Wr[(k4 * 4 + 1) * 128 + j], a);
            a = fmaf(c4.z, Wr[(k4 * 4 + 2) * 128 + j], a);
            a = fmaf(c4.w, Wr[(k4 * 4 + 3) * 128 + j], a);
        }
        C[(row0 + rr) * 128 + j] = a + bl[(size_t)lv[rr] * 128 + j];
    }
}

// ---------------- edge attention scores via MFMA ----------------
// 64 edges/block, 4 waves. Wave w owns output cols [32w, 32w+32).
// B (WcT rows = Wc cols) cached in registers; A gathered per edge-group of 16.
__global__ __launch_bounds__(256) void k_edge_mfma(
    const unsigned short* __restrict__ hbf, const float* __restrict__ ef,
    const int* __restrict__ eis, const int* __restrict__ eid,
    const unsigned short* __restrict__ WcT, const float* __restrict__ beff,
    const float* __restrict__ W2, const float* __restrict__ b2p,
    float* __restrict__ ebuf, float* __restrict__ z) {
    __shared__ float part[4][64];
    int tid = threadIdx.x;
    int w = tid >> 6, lane = tid & 63, lr = lane & 15, lg = lane >> 4;
    long e0 = (long)blockIdx.x * 64;
    long rem = ((long)EE - e0) / 16;
    int n16 = rem < 4 ? (int)rem : 4;

    bf16x8 Bf[2][10];
#pragma unroll
    for (int ct = 0; ct < 2; ct++) {
        const unsigned short* wp = WcT + (size_t)(w * 32 + ct * 16 + lr) * 320 + lg * 8;
#pragma unroll
        for (int kk = 0; kk < 10; kk++) Bf[ct][kk] = *(const bf16x8*)(wp + kk * 32);
    }
    int col0 = w * 32 + lr, col1 = col0 + 16;
    float be0 = beff[col0], be1 = beff[col1];
    float w20 = W2[col0], w21 = W2[col1];

    for (int i16 = 0; i16 < n16; i16++) {
        long e = e0 + i16 * 16 + lr;
        int s = eis[e], dd = eid[e];
        const unsigned short* hs = hbf + (size_t)s * 128 + lg * 8;
        const unsigned short* hd = hbf + (size_t)dd * 128 + lg * 8;
        f32x4 acc0 = {0.f, 0.f, 0.f, 0.f}, acc1 = {0.f, 0.f, 0.f, 0.f};
#pragma unroll
        for (int kk = 0; kk < 4; kk++) {
            bf16x8 a = *(const bf16x8*)(hs + kk * 32);
            acc0 = __builtin_amdgcn_mfma_f32_16x16x32_bf16(a, Bf[0][kk], acc0, 0, 0, 0);
            acc1 = __builtin_amdgcn_mfma_f32_16x16x32_bf16(a, Bf[1][kk], acc1, 0, 0, 0);
        }
#pragma unroll
        for (int kk = 0; kk < 4; kk++) {
            bf16x8 a = *(const bf16x8*)(hd + kk * 32);
            acc0 = __builtin_amdgcn_mfma_f32_16x16x32_bf16(a, Bf[0][kk + 4], acc0, 0, 0, 0);
            acc1 = __builtin_amdgcn_mfma_f32_16x16x32_bf16(a, Bf[1][kk + 4], acc1, 0, 0, 0);
        }
        const float* ep = ef + (size_t)e * 64 + lg * 8;
#pragma unroll
        for (int kk = 0; kk < 2; kk++) {
            float4 fa = *(const float4*)(ep + kk * 32);
            float4 fb = *(const float4*)(ep + kk * 32 + 4);
            bf16x8 a;
            a[0] = f2bf(fa.x); a[1] = f2bf(fa.y); a[2] = f2bf(fa.z); a[3] = f2bf(fa.w);
            a[4] = f2bf(fb.x); a[5] = f2bf(fb.y); a[6] = f2bf(fb.z); a[7] = f2bf(fb.w);
            acc0 = __builtin_amdgcn_mfma_f32_16x16x32_bf16(a, Bf[0][kk + 8], acc0, 0, 0, 0);
            acc1 = __builtin_amdgcn_mfma_f32_16x16x32_bf16(a, Bf[1][kk + 8], acc1, 0, 0, 0);
        }
#pragma unroll
        for (int i = 0; i < 4; i++) {
            float v = tanhf(acc0[i] + be0) * w20 + tanhf(acc1[i] + be1) * w21;
            v += __shfl_xor(v, 1);
            v += __shfl_xor(v, 2);
            v += __shfl_xor(v, 4);
            v += __shfl_xor(v, 8);
            if (lr == 0) part[w][i16 * 16 + lg * 4 + i] = v;
        }
    }
    __syncthreads();
    if (tid < n16 * 16) {
        long e = e0 + tid;
        float a = part[0][tid] + part[1][tid] + part[2][tid] + part[3][tid] + b2p[0];
        float ev = expf(a);
        ebuf[e] = ev;
        atomicAdd(&z[eis[e]], ev);
    }
}

// ---------------- aggregation: agg[s] += alpha * h[d] ----------------
__global__ __launch_bounds__(256) void k_agg(const float* __restrict__ h,
                                             const float* __restrict__ ebuf,
                                             const float* __restrict__ z,
                                             const int* __restrict__ eis,
                                             const int* __restrict__ eid,
                                             float* __restrict__ agg) {
    int tid = threadIdx.x;
    long e = (long)blockIdx.x * 2 + (tid >> 7);
    int j = tid & 127;
    int s = eis[e], dd = eid[e];
    float alpha = ebuf[e] / (z[s] + 1e-16f);
    atomicAdd(&agg[(size_t)s * 128 + j], alpha * h[(size_t)dd * 128 + j]);
}

// ---------------- per-node relation score ----------------
__global__ __launch_bounds__(256) void k_score(const float* __restrict__ emb,
                                               const float* __restrict__ W1,
                                               const float* __restrict__ b1,
                                               const float* __restrict__ W2,
                                               const float* __restrict__ b2p,
                                               float* __restrict__ scores, int t) {
    __shared__ __align__(16) float T[16][128];
    __shared__ float part[4][8];
    int tid = threadIdx.x;
    long row0 = (long)blockIdx.x * 16;
#pragma unroll
    for (int i = 0; i < 8; i++) {
        int idx = tid + i * 256;
        int r = idx >> 7, c = idx & 127;
        T[r][c] = emb[(row0 + r) * 128 + c];
    }
    __syncthreads();
    int j = tid & 127, half = tid >> 7;
    float acc[8] = {0, 0, 0, 0, 0, 0, 0, 0};
    for (int k4 = 0; k4 < 32; k4++) {
        float w0 = W1[(k4 * 4 + 0) * 128 + j];
        float w1 = W1[(k4 * 4 + 1) * 128 + j];
        float w2 = W1[(k4 * 4 + 2) * 128 + j];
        float w3 = W1[(k4 * 4 + 3) * 128 + j];
#pragma unroll
        for (int r = 0; r < 8; r++) {
            float4 c4 = *reinterpret_cast<const float4*>(&T[half * 8 + r][k4 * 4]);
            acc[r] = fmaf(c4.x, w0, acc[r]);
            acc[r] = fmaf(c4.y, w1, acc[r]);
            acc[r] = fmaf(c4.z, w2, acc[r]);
            acc[r] = fmaf(c4.w, w3, acc[r]);
        }
    }
    float bj = b1[j], w2j = W2[j];
#pragma unroll
    for (int r = 0; r < 8; r++) {
        float v = tanhf(acc[r] + bj) * w2j;
#pragma unroll
        for (int o = 32; o > 0; o >>= 1) v += __shfl_down(v, o);
        if ((tid & 63) == 0) part[tid >> 6][r] = v;
    }
    __syncthreads();
    if (tid < 16) {
        int hh = tid >> 3, r = tid & 7;
        float a = part[hh * 2][r] + part[hh * 2 + 1][r] + b2p[0];
        scores[(row0 + tid) * 2 + t] = a;
    }
}

// ---------------- level mean accumulate ----------------
__global__ __launch_bounds__(128) void k_lmean_acc(const float* __restrict__ hf,
                                                   const int* __restrict__ lev,
                                                   float* __restrict__ lsum,
                                                   float* __restrict__ cnt) {
    __shared__ float ls[4][128];
    __shared__ float lc[4];
    int tid = threadIdx.x;
#pragma unroll
    for (int l = 0; l < 4; l++) ls[l][tid] = 0.0f;
    if (tid < 4) lc[tid] = 0.0f;
    __syncthreads();
    long row0 = (long)blockIdx.x * 32;
    for (int r = 0; r < 32; r++) {
        long row = row0 + r;
        int l = lev[row];
        ls[l][tid] += hf[row * 128 + tid];
        if (tid == 0) lc[l] += 1.0f;
    }
    __syncthreads();
#pragma unroll
    for (int l = 0; l < 4; l++) atomicAdd(&lsum[l * 128 + tid], ls[l][tid]);
    if (tid < 4) atomicAdd(&cnt[tid], lc[tid]);
}

// ---------------- level mean finalize + lmean@W1b + b1 ----------------
__global__ void k_lmean_fin(const float* __restrict__ lsum, const float* __restrict__ cnt,
                            const float* __restrict__ W1b, const float* __restrict__ b1,
                            float* __restrict__ lmean, float* __restrict__ lmw) {
    __shared__ float lml[128];
    int l = blockIdx.x, tid = threadIdx.x;
    float c = cnt[l];
    c = c < 1.0f ? 1.0f : c;
    float v = lsum[l * 128 + tid] / c;
    lmean[l * 128 + tid] = v;
    lml[tid] = v;
    __syncthreads();
    float a = b1[tid];
    for (int k = 0; k < 128; k++) a = fmaf(lml[k], W1b[k * 128 + tid], a);
    lmw[l * 128 + tid] = a;
}

// ---------------- hierarchical attention ----------------
__global__ __launch_bounds__(256) void k_hier(const float* __restrict__ hfa,
                                              const float* __restrict__ lmw,
                                              const float* __restrict__ lmean,
                                              const float* __restrict__ W2,
                                              const float* __restrict__ b2p,
                                              float* __restrict__ enh) {
    __shared__ __align__(16) float T[16][128];
    __shared__ float lm[4][128];
    __shared__ float part[4][8][4];
    __shared__ float aw[16][4];
    int tid = threadIdx.x;
    long row0 = (long)blockIdx.x * 16;
#pragma unroll
    for (int i = 0; i < 8; i++) {
        int idx = tid + i * 256;
        T[idx >> 7][idx & 127] = hfa[(row0 + (idx >> 7)) * 128 + (idx & 127)];
    }
    for (int idx = tid; idx < 512; idx += 256) lm[idx >> 7][idx & 127] = lmean[idx];
    __syncthreads();
    int j = tid & 127, half = tid >> 7;
    float w2j = W2[j];
    float lw[4];
#pragma unroll
    for (int l = 0; l < 4; l++) lw[l] = lmw[l * 128 + j];
#pragma unroll
    for (int r = 0; r < 8; r++) {
        int rr = half * 8 + r;
        float hv = T[rr][j];
#pragma unroll
        for (int l = 0; l < 4; l++) {
            float v = tanhf(hv + lw[l]) * w2j;
#pragma unroll
            for (int o = 32; o > 0; o >>= 1) v += __shfl_down(v, o);
            if ((tid & 63) == 0) part[tid >> 6][r][l] = v;
        }
    }
    __syncthreads();
    if (tid < 16) {
        int hh = tid >> 3, r = tid & 7;
        float b2 = b2p[0];
        float sc[4];
        float mx = -1e30f;
#pragma unroll
        for (int l = 0; l < 4; l++) {
            sc[l] = part[hh * 2][r][l] + part[hh * 2 + 1][r][l] + b2;
            mx = fmaxf(mx, sc[l]);
        }
        float s = 0.0f;
#pragma unroll
        for (int l = 0; l < 4; l++) { sc[l] = expf(sc[l] - mx); s += sc[l]; }
        float inv = 1.0f / s;
#pragma unroll
        for (int l = 0; l < 4; l++) aw[tid][l] = sc[l] * inv;
    }
    __syncthreads();
#pragma unroll
    for (int r = 0; r < 8; r++) {
        int rr = half * 8 + r;
        float e = 0.0f;
#pragma unroll
        for (int l = 0; l < 4; l++) e = fmaf(aw[rr][l], lm[l][j], e);
        enh[(row0 + rr) * 128 + j] = e;
    }
}

extern "C" void kernel_launch(void* const* d_in, const int* in_sizes, int n_in,
                              void* d_out, int out_size, void* d_ws, size_t ws_size,
                              hipStream_t stream) {
    const float* nf  = (const float*)d_in[0];
    const float* ef  = (const float*)d_in[1];
    const int*   lev = (const int*)d_in[2];
    const int*   ei  = (const int*)d_in[3];
    const float* nlW = (const float*)d_in[4];
    const float* nlb = (const float*)d_in[5];
    const float* neW = (const float*)d_in[6];
    const float* neb = (const float*)d_in[7];
    const float* aW1 = (const float*)d_in[8];
    const float* ab1 = (const float*)d_in[9];
    const float* aW2 = (const float*)d_in[10];
    const float* ab2 = (const float*)d_in[11];
    const float* oW  = (const float*)d_in[12];
    const float* ob  = (const float*)d_in[13];
    const float* lng = (const float*)d_in[14];
    const float* lnb = (const float*)d_in[15];
    const float* eW1 = (const float*)d_in[16];
    const float* eb1 = (const float*)d_in[17];
    const float* eW2 = (const float*)d_in[18];
    const float* eb2 = (const float*)d_in[19];
    const float* eoW = (const float*)d_in[20];
    const float* eob = (const float*)d_in[21];
    const float* elg = (const float*)d_in[22];
    const float* elb = (const float*)d_in[23];
    const float* hpW = (const float*)d_in[24];
    const float* hpb = (const float*)d_in[25];
    const float* hW1 = (const float*)d_in[26];
    const float* hb1 = (const float*)d_in[27];
    const float* hW2 = (const float*)d_in[28];
    const float* hb2 = (const float*)d_in[29];
    const float* hoW = (const float*)d_in[30];
    const float* hob = (const float*)d_in[31];
    const float* hlg = (const float*)d_in[32];
    const float* hlb = (const float*)d_in[33];

    float* ws = (float*)d_ws;
    size_t NH = (size_t)NN * 128;
    float* h      = ws;
    float* ebuf   = h + NH;
    float* z      = ebuf + EE;
    float* agg    = z + NN;
    float* emb0   = agg + NH;
    float* emb1   = emb0 + NH;
    float* scores = emb1 + NH;
    float* beff   = scores + (size_t)NN * 2;
    float* lsum   = beff + 128;
    float* cnt    = lsum + 512;
    float* lmean  = cnt + 4;
    float* lmw    = lmean + 512;
    unsigned short* WcT = (unsigned short*)(lmw + 512);   // 128*320 bf16
    unsigned short* hbf = WcT + 128 * 320;                // NH bf16
    // aliases (lifetime-disjoint)
    float* fused = h;
    float* hfbuf = agg;
    float* hfa   = emb0;
    float* enh   = emb1;
    float* out   = (float*)d_out;

    for (int t = 0; t < 2; t++) {
        k_prep_edge2<<<129, 320, 0, stream>>>(aW1 + (size_t)t * 384 * 128,
                                              neW + (size_t)t * 64 * 128,
                                              neb + t * 128, ab1 + t * 128, WcT, beff);
        k_gemm_plain<<<NN / 16, 256, 0, stream>>>(nf, nlW + (size_t)t * 128 * 128,
                                                  nlb + t * 128, h);
        k_h2bf<<<2048, 256, 0, stream>>>(h, hbf, NH);
        k_zero<<<256, 256, 0, stream>>>(z, (size_t)NN);
        const int* eis = ei + (size_t)t * 2 * EE;
        const int* eid = eis + EE;
        k_edge_mfma<<<(EE + 63) / 64, 256, 0, stream>>>(hbf, ef + (size_t)t * EE * 64,
                                                        eis, eid, WcT, beff,
                                                        aW2 + t * 128, ab2 + t, ebuf, z);
        k_zero<<<2048, 256, 0, stream>>>(agg, NH);
        k_agg<<<EE / 2, 256, 0, stream>>>(h, ebuf, z, eis, eid, agg);
        float* embt = (t == 0) ? emb0 : emb1;
        k_gemm_ln<<<NN / 16, 256, 0, stream>>>(agg, oW + (size_t)t * 128 * 128,
                                               ob + t * 128, lng + t * 128, lnb + t * 128,
                                               embt);
        k_score<<<NN / 16, 256, 0, stream>>>(embt, eW1 + (size_t)t * 128 * 128,
                                             eb1 + t * 128, eW2 + t * 128, eb2 + t,
                                             scores, t);
    }
    k_fuse_gemm_ln<<<NN / 16, 256, 0, stream>>>(emb0, emb1, scores, eoW, eob, elg, elb,
                                                fused);
    k_gemm_level<<<NN / 16, 256, 0, stream>>>(fused, lev, hpW, hpb, hfbuf);
    k_zero<<<2, 256, 0, stream>>>(lsum, (size_t)516);
    k_lmean_acc<<<NN / 32, 128, 0, stream>>>(hfbuf, lev, lsum, cnt);
    k_gemm_plain<<<NN / 16, 256, 0, stream>>>(hfbuf, hW1, nullptr, hfa);
    k_lmean_fin<<<4, 128, 0, stream>>>(lsum, cnt, hW1 + 128 * 128, hb1, lmean, lmw);
    k_hier<<<NN / 16, 256, 0, stream>>>(hfa, lmw, lmean, hW2, hb2, enh);
    k_gemm_ln<<<NN / 16, 256, 0, stream>>>(enh, hoW, hob, hlg, hlb, out);
}

// Round 3
// 1656.420 us; speedup vs baseline: 2.1361x; 1.2393x over previous
//
#include <hip/hip_runtime.h>
#include <math.h>

#define NN 100000
#define EE 500000
// D=H=128, ED=64, T=2, L=4

typedef __attribute__((ext_vector_type(8))) short bf16x8;
typedef __attribute__((ext_vector_type(4))) float f32x4;
#define MFMA __builtin_amdgcn_mfma_f32_16x16x32_bf16

__device__ inline short f2bf(float x) {
    union { float f; unsigned u; } v; v.f = x;
    unsigned r = v.u + 0x7FFF + ((v.u >> 16) & 1);
    return (short)(r >> 16);
}
__device__ inline float bf2f(unsigned short h) {
    union { unsigned u; float f; } v; v.u = ((unsigned)h) << 16; return v.f;
}

__device__ inline bf16x8 mk_hi(const float* p) {
    float4 a = *(const float4*)p, b = *(const float4*)(p + 4);
    float v[8] = {a.x, a.y, a.z, a.w, b.x, b.y, b.z, b.w};
    bf16x8 h;
#pragma unroll
    for (int i = 0; i < 8; i++) h[i] = f2bf(v[i]);
    return h;
}
__device__ inline void mk_split(const float* p, bf16x8& hi, bf16x8& lo) {
    float4 a = *(const float4*)p, b = *(const float4*)(p + 4);
    float v[8] = {a.x, a.y, a.z, a.w, b.x, b.y, b.z, b.w};
#pragma unroll
    for (int i = 0; i < 8; i++) {
        short h = f2bf(v[i]);
        hi[i] = h;
        lo[i] = f2bf(v[i] - bf2f((unsigned short)h));
    }
}

// ---------------- zero fill ----------------
__global__ void k_zero(float* __restrict__ p, size_t n) {
    size_t i = (size_t)blockIdx.x * blockDim.x + threadIdx.x;
    size_t stride = (size_t)gridDim.x * blockDim.x;
    for (; i < n; i += stride) p[i] = 0.0f;
}

// ---------------- prep head: WhT, WUT, WVT, WET (bf16 transposed), beff ----------------
__global__ void k_prep_head(const float* __restrict__ Wn, const float* __restrict__ bn,
                            const float* __restrict__ W1, const float* __restrict__ b1,
                            const float* __restrict__ We, const float* __restrict__ be,
                            unsigned short* __restrict__ WhT, unsigned short* __restrict__ WUT,
                            unsigned short* __restrict__ WVT, unsigned short* __restrict__ WET,
                            float* __restrict__ beff) {
    __shared__ float red[2];
    int j = blockIdx.x, k = threadIdx.x;  // 128 blocks x 128 threads
    WhT[j * 128 + k] = (unsigned short)f2bf(Wn[k * 128 + j]);
    float su = 0.0f, sv = 0.0f;
    for (int m = 0; m < 128; m++) {
        float wkm = Wn[k * 128 + m];
        su = fmaf(wkm, W1[m * 128 + j], su);
        sv = fmaf(wkm, W1[(128 + m) * 128 + j], sv);
    }
    WUT[j * 128 + k] = (unsigned short)f2bf(su);
    WVT[j * 128 + k] = (unsigned short)f2bf(sv);
    if (k < 64) {
        float se = 0.0f;
        for (int m = 0; m < 128; m++) se = fmaf(We[k * 128 + m], W1[(256 + m) * 128 + j], se);
        WET[j * 64 + k] = (unsigned short)f2bf(se);
    }
    float tk = bn[k] * (W1[k * 128 + j] + W1[(128 + k) * 128 + j]) + be[k] * W1[(256 + k) * 128 + j];
#pragma unroll
    for (int o = 32; o > 0; o >>= 1) tk += __shfl_down(tk, o);
    if ((k & 63) == 0) red[k >> 6] = tk;
    __syncthreads();
    if (k == 0) beff[j] = b1[j] + red[0] + red[1];
}

// ---------------- prep tail: split-bf16 transposed weights (11 mats) ----------------
struct WSrc { const float* s[11]; };
__global__ void k_prep_tail(WSrc ps, unsigned short* __restrict__ hi,
                            unsigned short* __restrict__ lo) {
    int m = blockIdx.x >> 6, blk = blockIdx.x & 63;
    const float* src = ps.s[m];
    unsigned short* h = hi + (size_t)m * 16384;
    unsigned short* l = lo + (size_t)m * 16384;
    int idx = blk * 256 + threadIdx.x;  // 0..16383
    int k = idx >> 7, j = idx & 127;
    float v = src[idx];
    short hh = f2bf(v);
    h[j * 128 + k] = (unsigned short)hh;
    l[j * 128 + k] = (unsigned short)f2bf(v - bf2f((unsigned short)hh));
}

// ---------------- HEAD: hbf = bf16(nf@Wn+bn), U = bf16(nf@WU), V = bf16(nf@WV) ----------------
__global__ __launch_bounds__(256) void k_head(const float* __restrict__ nf,
                                              const unsigned short* __restrict__ WhT,
                                              const unsigned short* __restrict__ WUT,
                                              const unsigned short* __restrict__ WVT,
                                              const float* __restrict__ bn,
                                              unsigned short* __restrict__ hbf,
                                              unsigned short* __restrict__ U,
                                              unsigned short* __restrict__ V) {
    __shared__ __align__(16) float T[16][132];
    int tid = threadIdx.x;
    long row0 = (long)blockIdx.x * 16;
#pragma unroll
    for (int i = 0; i < 8; i++) {
        int idx = tid + i * 256;
        int r = idx >> 7, c = idx & 127;
        T[r][c] = nf[(row0 + r) * 128 + c];
    }
    __syncthreads();
    int w = tid >> 6, lane = tid & 63, lr = lane & 15, lg = lane >> 4;
    bf16x8 A[4];
#pragma unroll
    for (int k = 0; k < 4; k++) A[k] = mk_hi(&T[lr][k * 32 + lg * 8]);
    int col0 = w * 32 + lr, col1 = col0 + 16;
#pragma unroll
    for (int o = 0; o < 3; o++) {
        const unsigned short* wb = (o == 0) ? WhT : (o == 1) ? WUT : WVT;
        unsigned short* ob = (o == 0) ? hbf : (o == 1) ? U : V;
        const unsigned short* w0 = wb + (size_t)col0 * 128 + lg * 8;
        const unsigned short* w1 = wb + (size_t)col1 * 128 + lg * 8;
        f32x4 a0 = {0.f, 0.f, 0.f, 0.f}, a1 = {0.f, 0.f, 0.f, 0.f};
#pragma unroll
        for (int k = 0; k < 4; k++) {
            a0 = MFMA(A[k], *(const bf16x8*)(w0 + k * 32), a0, 0, 0, 0);
            a1 = MFMA(A[k], *(const bf16x8*)(w1 + k * 32), a1, 0, 0, 0);
        }
        float bb0 = (o == 0) ? bn[col0] : 0.0f;
        float bb1 = (o == 0) ? bn[col1] : 0.0f;
        unsigned short* op = ob + (size_t)row0 * 128;
#pragma unroll
        for (int i = 0; i < 4; i++) {
            int r = lg * 4 + i;
            op[(size_t)r * 128 + col0] = (unsigned short)f2bf(a0[i] + bb0);
            op[(size_t)r * 128 + col1] = (unsigned short)f2bf(a1[i] + bb1);
        }
    }
}

// ---------------- EDGE: pre = U[s]+V[d]+ef@WE+beff; score=tanh(pre)@W2+b2; e=exp ----------------
__global__ __launch_bounds__(256) void k_edge2(const float* __restrict__ ef,
                                               const int* __restrict__ eis,
                                               const int* __restrict__ eid,
                                               const unsigned short* __restrict__ WET,
                                               const unsigned short* __restrict__ U,
                                               const unsigned short* __restrict__ V,
                                               const float* __restrict__ beff,
                                               const float* __restrict__ W2,
                                               const float* __restrict__ b2p,
                                               float* __restrict__ ebuf,
                                               float* __restrict__ z) {
    __shared__ float part[4][64];
    int tid = threadIdx.x, w = tid >> 6, lane = tid & 63, lr = lane & 15, lg = lane >> 4;
    long e0 = (long)blockIdx.x * 64;
    long rem = ((long)EE - e0) / 16;
    int n16 = rem < 4 ? (int)rem : 4;
    int col0 = w * 32 + lr, col1 = col0 + 16;
    bf16x8 B0[2], B1[2];
#pragma unroll
    for (int kk = 0; kk < 2; kk++) {
        B0[kk] = *(const bf16x8*)(WET + (size_t)col0 * 64 + kk * 32 + lg * 8);
        B1[kk] = *(const bf16x8*)(WET + (size_t)col1 * 64 + kk * 32 + lg * 8);
    }
    float be0 = beff[col0], be1 = beff[col1], w20 = W2[col0], w21 = W2[col1];
    for (int i16 = 0; i16 < n16; i16++) {
        long eg0 = e0 + i16 * 16;
        const float* ep = ef + (size_t)(eg0 + lr) * 64;
        f32x4 a0 = {0.f, 0.f, 0.f, 0.f}, a1 = {0.f, 0.f, 0.f, 0.f};
#pragma unroll
        for (int kk = 0; kk < 2; kk++) {
            bf16x8 a = mk_hi(ep + kk * 32 + lg * 8);
            a0 = MFMA(a, B0[kk], a0, 0, 0, 0);
            a1 = MFMA(a, B1[kk], a1, 0, 0, 0);
        }
        int4 s4 = *(const int4*)(eis + eg0 + lg * 4);
        int4 d4 = *(const int4*)(eid + eg0 + lg * 4);
        int ss[4] = {s4.x, s4.y, s4.z, s4.w};
        int dd[4] = {d4.x, d4.y, d4.z, d4.w};
#pragma unroll
        for (int i = 0; i < 4; i++) {
            float u0 = bf2f(U[(size_t)ss[i] * 128 + col0]) + bf2f(V[(size_t)dd[i] * 128 + col0]);
            float u1 = bf2f(U[(size_t)ss[i] * 128 + col1]) + bf2f(V[(size_t)dd[i] * 128 + col1]);
            float v = tanhf(a0[i] + u0 + be0) * w20 + tanhf(a1[i] + u1 + be1) * w21;
            v += __shfl_xor(v, 1);
            v += __shfl_xor(v, 2);
            v += __shfl_xor(v, 4);
            v += __shfl_xor(v, 8);
            if (lr == 0) part[w][i16 * 16 + lg * 4 + i] = v;
        }
    }
    __syncthreads();
    if (tid < n16 * 16) {
        long e = e0 + tid;
        float a = part[0][tid] + part[1][tid] + part[2][tid] + part[3][tid] + b2p[0];
        float ev = expf(a);
        ebuf[e] = ev;
        atomicAdd(&z[eis[e]], ev);
    }
}

// ---------------- AGG: agg[s] += e * h[d]  (unnormalized; /z deferred) ----------------
__global__ __launch_bounds__(256) void k_agg2(const unsigned short* __restrict__ hbf,
                                              const float* __restrict__ ebuf,
                                              const int* __restrict__ eis,
                                              const int* __restrict__ eid,
                                              float* __restrict__ agg) {
    int tid = threadIdx.x;
    long e = (long)blockIdx.x * 2 + (tid >> 7);
    int j = tid & 127;
    int s = eis[e], d = eid[e];
    float wv = ebuf[e];
    atomicAdd(&agg[(size_t)s * 128 + j], wv * bf2f(hbf[(size_t)d * 128 + j]));
}

// ---------------- TAIL-A: emb = relu(LN((agg/z)@oW+ob)); score = tanh(emb@eW1+eb1)@eW2+eb2 ----
__global__ __launch_bounds__(256) void k_tailA(const float* __restrict__ agg,
                                               const float* __restrict__ z,
                                               const unsigned short* __restrict__ Whi,
                                               const unsigned short* __restrict__ Wlo,
                                               const float* __restrict__ ob,
                                               const float* __restrict__ g,
                                               const float* __restrict__ bln,
                                               const unsigned short* __restrict__ Shi,
                                               const unsigned short* __restrict__ Slo,
                                               const float* __restrict__ sb1,
                                               const float* __restrict__ sW2,
                                               const float* __restrict__ sb2,
                                               float* __restrict__ emb,
                                               float* __restrict__ scores, int t) {
    __shared__ __align__(16) float T[16][132];
    __shared__ __align__(16) float T2[16][132];
    __shared__ float mu16[16], rs16[16], zs[16], part[4][16];
    int tid = threadIdx.x;
    long row0 = (long)blockIdx.x * 16;
    if (tid < 16) zs[tid] = 1.0f / (z[row0 + tid] + 1e-16f);
    __syncthreads();
#pragma unroll
    for (int i = 0; i < 8; i++) {
        int idx = tid + i * 256;
        int r = idx >> 7, c = idx & 127;
        T[r][c] = agg[(row0 + r) * 128 + c] * zs[r];
    }
    __syncthreads();
    int w = tid >> 6, lane = tid & 63, lr = lane & 15, lg = lane >> 4;
    int col0 = w * 32 + lr, col1 = col0 + 16;
    int j = tid & 127, half = tid >> 7;
    {
        bf16x8 ahi[4], alo[4];
#pragma unroll
        for (int k = 0; k < 4; k++) mk_split(&T[lr][k * 32 + lg * 8], ahi[k], alo[k]);
        const unsigned short* wh0 = Whi + (size_t)col0 * 128 + lg * 8;
        const unsigned short* wl0 = Wlo + (size_t)col0 * 128 + lg * 8;
        const unsigned short* wh1 = Whi + (size_t)col1 * 128 + lg * 8;
        const unsigned short* wl1 = Wlo + (size_t)col1 * 128 + lg * 8;
        f32x4 a0 = {0.f, 0.f, 0.f, 0.f}, a1 = {0.f, 0.f, 0.f, 0.f};
#pragma unroll
        for (int k = 0; k < 4; k++) {
            bf16x8 bh = *(const bf16x8*)(wh0 + k * 32), bl = *(const bf16x8*)(wl0 + k * 32);
            a0 = MFMA(ahi[k], bh, a0, 0, 0, 0);
            a0 = MFMA(alo[k], bh, a0, 0, 0, 0);
            a0 = MFMA(ahi[k], bl, a0, 0, 0, 0);
            bh = *(const bf16x8*)(wh1 + k * 32); bl = *(const bf16x8*)(wl1 + k * 32);
            a1 = MFMA(ahi[k], bh, a1, 0, 0, 0);
            a1 = MFMA(alo[k], bh, a1, 0, 0, 0);
            a1 = MFMA(ahi[k], bl, a1, 0, 0, 0);
        }
#pragma unroll
        for (int i = 0; i < 4; i++) {
            int r = lg * 4 + i;
            T2[r][col0] = a0[i] + ob[col0];
            T2[r][col1] = a1[i] + ob[col1];
        }
    }
    __syncthreads();
    {
        int gr = tid >> 4, l16 = tid & 15;
        float sm = 0.0f, sq = 0.0f;
#pragma unroll
        for (int i = 0; i < 8; i++) {
            float v = T2[gr][l16 + 16 * i];
            sm += v; sq += v * v;
        }
#pragma unroll
        for (int m = 1; m < 16; m <<= 1) { sm += __shfl_xor(sm, m); sq += __shfl_xor(sq, m); }
        if (l16 == 0) {
            float mean = sm * (1.0f / 128.0f);
            float var = sq * (1.0f / 128.0f) - mean * mean;
            mu16[gr] = mean;
            rs16[gr] = rsqrtf(var + 1e-5f);
        }
    }
    __syncthreads();
    {
        float gj = g[j], bb = bln[j];
#pragma unroll
        for (int r = 0; r < 8; r++) {
            int rr = half * 8 + r;
            float v = fmaxf((T2[rr][j] - mu16[rr]) * rs16[rr] * gj + bb, 0.0f);
            emb[(row0 + rr) * 128 + j] = v;
            T2[rr][j] = v;
        }
    }
    __syncthreads();
    {
        bf16x8 ahi[4], alo[4];
#pragma unroll
        for (int k = 0; k < 4; k++) mk_split(&T2[lr][k * 32 + lg * 8], ahi[k], alo[k]);
        const unsigned short* wh0 = Shi + (size_t)col0 * 128 + lg * 8;
        const unsigned short* wl0 = Slo + (size_t)col0 * 128 + lg * 8;
        const unsigned short* wh1 = Shi + (size_t)col1 * 128 + lg * 8;
        const unsigned short* wl1 = Slo + (size_t)col1 * 128 + lg * 8;
        f32x4 a0 = {0.f, 0.f, 0.f, 0.f}, a1 = {0.f, 0.f, 0.f, 0.f};
#pragma unroll
        for (int k = 0; k < 4; k++) {
            bf16x8 bh = *(const bf16x8*)(wh0 + k * 32), bl = *(const bf16x8*)(wl0 + k * 32);
            a0 = MFMA(ahi[k], bh, a0, 0, 0, 0);
            a0 = MFMA(alo[k], bh, a0, 0, 0, 0);
            a0 = MFMA(ahi[k], bl, a0, 0, 0, 0);
            bh = *(const bf16x8*)(wh1 + k * 32); bl = *(const bf16x8*)(wl1 + k * 32);
            a1 = MFMA(ahi[k], bh, a1, 0, 0, 0);
            a1 = MFMA(alo[k], bh, a1, 0, 0, 0);
            a1 = MFMA(ahi[k], bl, a1, 0, 0, 0);
        }
        float b0 = sb1[col0], b1v = sb1[col1], w20 = sW2[col0], w21 = sW2[col1];
#pragma unroll
        for (int i = 0; i < 4; i++) {
            int r = lg * 4 + i;
            float v = tanhf(a0[i] + b0) * w20 + tanhf(a1[i] + b1v) * w21;
            v += __shfl_xor(v, 1);
            v += __shfl_xor(v, 2);
            v += __shfl_xor(v, 4);
            v += __shfl_xor(v, 8);
            if (lr == 0) part[w][r] = v;
        }
    }
    __syncthreads();
    if (tid < 16)
        scores[(row0 + tid) * 2 + t] = part[0][tid] + part[1][tid] + part[2][tid] + part[3][tid] + sb2[0];
}

// ---------------- TAIL-B: fuse -> eoW LN relu -> level GEMM (all 4, select) -> lsum + hfa ----
__global__ __launch_bounds__(256) void k_tailB(const float* __restrict__ emb0,
                                               const float* __restrict__ emb1,
                                               const float* __restrict__ scores,
                                               const int* __restrict__ lev,
                                               const unsigned short* __restrict__ Fhi,
                                               const unsigned short* __restrict__ Flo,
                                               const float* __restrict__ eob,
                                               const float* __restrict__ elg,
                                               const float* __restrict__ elb,
                                               const unsigned short* __restrict__ Phi,
                                               const unsigned short* __restrict__ Plo,
                                               const float* __restrict__ hpb,
                                               const unsigned short* __restrict__ Ahi,
                                               const unsigned short* __restrict__ Alo,
                                               float* __restrict__ hfa,
                                               float* __restrict__ lsum,
                                               float* __restrict__ cnt) {
    __shared__ __align__(16) float T[16][132];
    __shared__ __align__(16) float T2[16][132];
    __shared__ float mu16[16], rs16[16], w0s[16], w1s[16];
    __shared__ float ls[4][128];
    __shared__ int lv[16];
    int tid = threadIdx.x;
    long row0 = (long)blockIdx.x * 16;
    if (tid < 16) {
        long r = row0 + tid;
        float s0 = scores[r * 2], s1 = scores[r * 2 + 1];
        float mx = fmaxf(s0, s1);
        float e0 = expf(s0 - mx), e1 = expf(s1 - mx);
        float inv = 1.0f / (e0 + e1);
        w0s[tid] = e0 * inv;
        w1s[tid] = e1 * inv;
        lv[tid] = lev[r];
    }
    for (int idx = tid; idx < 512; idx += 256) ((float*)ls)[idx] = 0.0f;
    __syncthreads();
#pragma unroll
    for (int i = 0; i < 8; i++) {
        int idx = tid + i * 256;
        int r = idx >> 7, c = idx & 127;
        T[r][c] = w0s[r] * emb0[(row0 + r) * 128 + c] + w1s[r] * emb1[(row0 + r) * 128 + c];
    }
    __syncthreads();
    int w = tid >> 6, lane = tid & 63, lr = lane & 15, lg = lane >> 4;
    int col0 = w * 32 + lr, col1 = col0 + 16;
    int j = tid & 127, half = tid >> 7;
    {
        bf16x8 ahi[4], alo[4];
#pragma unroll
        for (int k = 0; k < 4; k++) mk_split(&T[lr][k * 32 + lg * 8], ahi[k], alo[k]);
        const unsigned short* wh0 = Fhi + (size_t)col0 * 128 + lg * 8;
        const unsigned short* wl0 = Flo + (size_t)col0 * 128 + lg * 8;
        const unsigned short* wh1 = Fhi + (size_t)col1 * 128 + lg * 8;
        const unsigned short* wl1 = Flo + (size_t)col1 * 128 + lg * 8;
        f32x4 a0 = {0.f, 0.f, 0.f, 0.f}, a1 = {0.f, 0.f, 0.f, 0.f};
#pragma unroll
        for (int k = 0; k < 4; k++) {
            bf16x8 bh = *(const bf16x8*)(wh0 + k * 32), bl = *(const bf16x8*)(wl0 + k * 32);
            a0 = MFMA(ahi[k], bh, a0, 0, 0, 0);
            a0 = MFMA(alo[k], bh, a0, 0, 0, 0);
            a0 = MFMA(ahi[k], bl, a0, 0, 0, 0);
            bh = *(const bf16x8*)(wh1 + k * 32); bl = *(const bf16x8*)(wl1 + k * 32);
            a1 = MFMA(ahi[k], bh, a1, 0, 0, 0);
            a1 = MFMA(alo[k], bh, a1, 0, 0, 0);
            a1 = MFMA(ahi[k], bl, a1, 0, 0, 0);
        }
#pragma unroll
        for (int i = 0; i < 4; i++) {
            int r = lg * 4 + i;
            T2[r][col0] = a0[i] + eob[col0];
            T2[r][col1] = a1[i] + eob[col1];
        }
    }
    __syncthreads();
    {
        int gr = tid >> 4, l16 = tid & 15;
        float sm = 0.0f, sq = 0.0f;
#pragma unroll
        for (int i = 0; i < 8; i++) {
            float v = T2[gr][l16 + 16 * i];
            sm += v; sq += v * v;
        }
#pragma unroll
        for (int m = 1; m < 16; m <<= 1) { sm += __shfl_xor(sm, m); sq += __shfl_xor(sq, m); }
        if (l16 == 0) {
            float mean = sm * (1.0f / 128.0f);
            float var = sq * (1.0f / 128.0f) - mean * mean;
            mu16[gr] = mean;
            rs16[gr] = rsqrtf(var + 1e-5f);
        }
    }
    __syncthreads();
    {
        float gj = elg[j], bb = elb[j];
#pragma unroll
        for (int r = 0; r < 8; r++) {
            int rr = half * 8 + r;
            T2[rr][j] = fmaxf((T2[rr][j] - mu16[rr]) * rs16[rr] * gj + bb, 0.0f);
        }
    }
    __syncthreads();
    // level GEMM: compute all 4 levels, select per row
    {
        bf16x8 ahi[4], alo[4];
#pragma unroll
        for (int k = 0; k < 4; k++) mk_split(&T2[lr][k * 32 + lg * 8], ahi[k], alo[k]);
        float sel0[4] = {0.f, 0.f, 0.f, 0.f}, sel1[4] = {0.f, 0.f, 0.f, 0.f};
#pragma unroll
        for (int l = 0; l < 4; l++) {
            const unsigned short* wh0 = Phi + (size_t)l * 16384 + (size_t)col0 * 128 + lg * 8;
            const unsigned short* wl0 = Plo + (size_t)l * 16384 + (size_t)col0 * 128 + lg * 8;
            const unsigned short* wh1 = Phi + (size_t)l * 16384 + (size_t)col1 * 128 + lg * 8;
            const unsigned short* wl1 = Plo + (size_t)l * 16384 + (size_t)col1 * 128 + lg * 8;
            f32x4 a0 = {0.f, 0.f, 0.f, 0.f}, a1 = {0.f, 0.f, 0.f, 0.f};
#pragma unroll
            for (int k = 0; k < 4; k++) {
                bf16x8 bh = *(const bf16x8*)(wh0 + k * 32), bl = *(const bf16x8*)(wl0 + k * 32);
                a0 = MFMA(ahi[k], bh, a0, 0, 0, 0);
                a0 = MFMA(alo[k], bh, a0, 0, 0, 0);
                a0 = MFMA(ahi[k], bl, a0, 0, 0, 0);
                bh = *(const bf16x8*)(wh1 + k * 32); bl = *(const bf16x8*)(wl1 + k * 32);
                a1 = MFMA(ahi[k], bh, a1, 0, 0, 0);
                a1 = MFMA(alo[k], bh, a1, 0, 0, 0);
                a1 = MFMA(ahi[k], bl, a1, 0, 0, 0);
            }
#pragma unroll
            for (int i = 0; i < 4; i++) {
                int r = lg * 4 + i;
                bool m = (lv[r] == l);
                sel0[i] = m ? (a0[i] + hpb[l * 128 + col0]) : sel0[i];
                sel1[i] = m ? (a1[i] + hpb[l * 128 + col1]) : sel1[i];
            }
        }
#pragma unroll
        for (int i = 0; i < 4; i++) {
            int r = lg * 4 + i;
            T[r][col0] = sel0[i];
            T[r][col1] = sel1[i];
            atomicAdd(&ls[lv[r]][col0], sel0[i]);
            atomicAdd(&ls[lv[r]][col1], sel1[i]);
        }
    }
    __syncthreads();
    for (int p = 0; p < 2; p++) {
        int idx = tid + p * 256;
        float v = ((float*)ls)[idx];
        if (v != 0.0f) atomicAdd(&lsum[idx], v);
        else atomicAdd(&lsum[idx], 0.0f);
    }
    if (tid < 4) {
        float c = 0.0f;
        for (int r = 0; r < 16; r++) c += (lv[r] == tid) ? 1.0f : 0.0f;
        atomicAdd(&cnt[tid], c);
    }
    // hfa = hf @ hW1a
    {
        bf16x8 ahi[4], alo[4];
#pragma unroll
        for (int k = 0; k < 4; k++) mk_split(&T[lr][k * 32 + lg * 8], ahi[k], alo[k]);
        const unsigned short* wh0 = Ahi + (size_t)col0 * 128 + lg * 8;
        const unsigned short* wl0 = Alo + (size_t)col0 * 128 + lg * 8;
        const unsigned short* wh1 = Ahi + (size_t)col1 * 128 + lg * 8;
        const unsigned short* wl1 = Alo + (size_t)col1 * 128 + lg * 8;
        f32x4 a0 = {0.f, 0.f, 0.f, 0.f}, a1 = {0.f, 0.f, 0.f, 0.f};
#pragma unroll
        for (int k = 0; k < 4; k++) {
            bf16x8 bh = *(const bf16x8*)(wh0 + k * 32), bl = *(const bf16x8*)(wl0 + k * 32);
            a0 = MFMA(ahi[k], bh, a0, 0, 0, 0);
            a0 = MFMA(alo[k], bh, a0, 0, 0, 0);
            a0 = MFMA(ahi[k], bl, a0, 0, 0, 0);
            bh = *(const bf16x8*)(wh1 + k * 32); bl = *(const bf16x8*)(wl1 + k * 32);
            a1 = MFMA(ahi[k], bh, a1, 0, 0, 0);
            a1 = MFMA(alo[k], bh, a1, 0, 0, 0);
            a1 = MFMA(ahi[k], bl, a1, 0, 0, 0);
        }
#pragma unroll
        for (int i = 0; i < 4; i++) {
            int r = lg * 4 + i;
            hfa[(row0 + r) * 128 + col0] = a0[i];
            hfa[(row0 + r) * 128 + col1] = a1[i];
        }
    }
}

// ---------------- level mean finalize + lmean@W1b + b1 ----------------
__global__ void k_lmean_fin(const float* __restrict__ lsum, const float* __restrict__ cnt,
                            const float* __restrict__ W1b, const float* __restrict__ b1,
                            float* __restrict__ lmean, float* __restrict__ lmw) {
    __shared__ float lml[128];
    int l = blockIdx.x, tid = threadIdx.x;
    float c = cnt[l];
    c = c < 1.0f ? 1.0f : c;
    float v = lsum[l * 128 + tid] / c;
    lmean[l * 128 + tid] = v;
    lml[tid] = v;
    __syncthreads();
    float a = b1[tid];
    for (int k = 0; k < 128; k++) a = fmaf(lml[k], W1b[k * 128 + tid], a);
    lmw[l * 128 + tid] = a;
}

// ---------------- TAIL-D: hier attention + final GEMM + LN + relu -> out ----------------
__global__ __launch_bounds__(256) void k_tailD(const float* __restrict__ hfa,
                                               const float* __restrict__ lmw,
                                               const float* __restrict__ lmean,
                                               const float* __restrict__ hW2,
                                               const float* __restrict__ hb2,
                                               const unsigned short* __restrict__ Ohi,
                                               const unsigned short* __restrict__ Olo,
                                               const float* __restrict__ hob,
                                               const float* __restrict__ hlg,
                                               const float* __restrict__ hlb,
                                               float* __restrict__ out) {
    __shared__ __align__(16) float T[16][132];
    __shared__ __align__(16) float T2[16][132];
    __shared__ float lm[4][128];
    __shared__ float part[4][8][4];
    __shared__ float aw[16][4];
    __shared__ float mu16[16], rs16[16];
    int tid = threadIdx.x;
    long row0 = (long)blockIdx.x * 16;
#pragma unroll
    for (int i = 0; i < 8; i++) {
        int idx = tid + i * 256;
        T[idx >> 7][idx & 127] = hfa[(row0 + (idx >> 7)) * 128 + (idx & 127)];
    }
    for (int idx = tid; idx < 512; idx += 256) lm[idx >> 7][idx & 127] = lmean[idx];
    __syncthreads();
    int j = tid & 127, half = tid >> 7;
    {
        float w2j = hW2[j];
        float lw[4];
#pragma unroll
        for (int l = 0; l < 4; l++) lw[l] = lmw[l * 128 + j];
#pragma unroll
        for (int r = 0; r < 8; r++) {
            int rr = half * 8 + r;
            float hv = T[rr][j];
#pragma unroll
            for (int l = 0; l < 4; l++) {
                float v = tanhf(hv + lw[l]) * w2j;
#pragma unroll
                for (int o = 32; o > 0; o >>= 1) v += __shfl_down(v, o);
                if ((tid & 63) == 0) part[tid >> 6][r][l] = v;
            }
        }
    }
    __syncthreads();
    if (tid < 16) {
        int hh = tid >> 3, r = tid & 7;
        float b2 = hb2[0];
        float sc[4];
        float mx = -1e30f;
#pragma unroll
        for (int l = 0; l < 4; l++) {
            sc[l] = part[hh * 2][r][l] + part[hh * 2 + 1][r][l] + b2;
            mx = fmaxf(mx, sc[l]);
        }
        float s = 0.0f;
#pragma unroll
        for (int l = 0; l < 4; l++) { sc[l] = expf(sc[l] - mx); s += sc[l]; }
        float inv = 1.0f / s;
#pragma unroll
        for (int l = 0; l < 4; l++) aw[tid][l] = sc[l] * inv;
    }
    __syncthreads();
#pragma unroll
    for (int r = 0; r < 8; r++) {
        int rr = half * 8 + r;
        float e = 0.0f;
#pragma unroll
        for (int l = 0; l < 4; l++) e = fmaf(aw[rr][l], lm[l][j], e);
        T2[rr][j] = e;
    }
    __syncthreads();
    int w = tid >> 6, lane = tid & 63, lr = lane & 15, lg = lane >> 4;
    int col0 = w * 32 + lr, col1 = col0 + 16;
    {
        bf16x8 ahi[4], alo[4];
#pragma unroll
        for (int k = 0; k < 4; k++) mk_split(&T2[lr][k * 32 + lg * 8], ahi[k], alo[k]);
        const unsigned short* wh0 = Ohi + (size_t)col0 * 128 + lg * 8;
        const unsigned short* wl0 = Olo + (size_t)col0 * 128 + lg * 8;
        const unsigned short* wh1 = Ohi + (size_t)col1 * 128 + lg * 8;
        const unsigned short* wl1 = Olo + (size_t)col1 * 128 + lg * 8;
        f32x4 a0 = {0.f, 0.f, 0.f, 0.f}, a1 = {0.f, 0.f, 0.f, 0.f};
#pragma unroll
        for (int k = 0; k < 4; k++) {
            bf16x8 bh = *(const bf16x8*)(wh0 + k * 32), bl = *(const bf16x8*)(wl0 + k * 32);
            a0 = MFMA(ahi[k], bh, a0, 0, 0, 0);
            a0 = MFMA(alo[k], bh, a0, 0, 0, 0);
            a0 = MFMA(ahi[k], bl, a0, 0, 0, 0);
            bh = *(const bf16x8*)(wh1 + k * 32); bl = *(const bf16x8*)(wl1 + k * 32);
            a1 = MFMA(ahi[k], bh, a1, 0, 0, 0);
            a1 = MFMA(alo[k], bh, a1, 0, 0, 0);
            a1 = MFMA(ahi[k], bl, a1, 0, 0, 0);
        }
#pragma unroll
        for (int i = 0; i < 4; i++) {
            int r = lg * 4 + i;
            T[r][col0] = a0[i] + hob[col0];
            T[r][col1] = a1[i] + hob[col1];
        }
    }
    __syncthreads();
    {
        int gr = tid >> 4, l16 = tid & 15;
        float sm = 0.0f, sq = 0.0f;
#pragma unroll
        for (int i = 0; i < 8; i++) {
            float v = T[gr][l16 + 16 * i];
            sm += v; sq += v * v;
        }
#pragma unroll
        for (int m = 1; m < 16; m <<= 1) { sm += __shfl_xor(sm, m); sq += __shfl_xor(sq, m); }
        if (l16 == 0) {
            float mean = sm * (1.0f / 128.0f);
            float var = sq * (1.0f / 128.0f) - mean * mean;
            mu16[gr] = mean;
            rs16[gr] = rsqrtf(var + 1e-5f);
        }
    }
    __syncthreads();
    {
        float gj = hlg[j], bb = hlb[j];
#pragma unroll
        for (int r = 0; r < 8; r++) {
            int rr = half * 8 + r;
            float v = (T[rr][j] - mu16[rr]) * rs16[rr] * gj + bb;
            out[(row0 + rr) * 128 + j] = fmaxf(v, 0.0f);
        }
    }
}

extern "C" void kernel_launch(void* const* d_in, const int* in_sizes, int n_in,
                              void* d_out, int out_size, void* d_ws, size_t ws_size,
                              hipStream_t stream) {
    const float* nf  = (const float*)d_in[0];
    const float* ef  = (const float*)d_in[1];
    const int*   lev = (const int*)d_in[2];
    const int*   ei  = (const int*)d_in[3];
    const float* nlW = (const float*)d_in[4];
    const float* nlb = (const float*)d_in[5];
    const float* neW = (const float*)d_in[6];
    const float* neb = (const float*)d_in[7];
    const float* aW1 = (const float*)d_in[8];
    const float* ab1 = (const float*)d_in[9];
    const float* aW2 = (const float*)d_in[10];
    const float* ab2 = (const float*)d_in[11];
    const float* oW  = (const float*)d_in[12];
    const float* ob  = (const float*)d_in[13];
    const float* lng = (const float*)d_in[14];
    const float* lnb = (const float*)d_in[15];
    const float* eW1 = (const float*)d_in[16];
    const float* eb1 = (const float*)d_in[17];
    const float* eW2 = (const float*)d_in[18];
    const float* eb2 = (const float*)d_in[19];
    const float* eoW = (const float*)d_in[20];
    const float* eob = (const float*)d_in[21];
    const float* elg = (const float*)d_in[22];
    const float* elb = (const float*)d_in[23];
    const float* hpW = (const float*)d_in[24];
    const float* hpb = (const float*)d_in[25];
    const float* hW1 = (const float*)d_in[26];
    const float* hb1 = (const float*)d_in[27];
    const float* hW2 = (const float*)d_in[28];
    const float* hb2 = (const float*)d_in[29];
    const float* hoW = (const float*)d_in[30];
    const float* hob = (const float*)d_in[31];
    const float* hlg = (const float*)d_in[32];
    const float* hlb = (const float*)d_in[33];

    float* ws = (float*)d_ws;
    size_t NH = (size_t)NN * 128;
    float* agg    = ws;              // NH (later reused as hfa)
    float* emb0   = agg + NH;        // NH
    float* emb1   = emb0 + NH;       // NH (hbf aliased here)
    float* ebuf   = emb1 + NH;       // EE
    float* z      = ebuf + EE;       // NN
    float* scores = z + NN;          // 2*NN
    float* beff   = scores + (size_t)2 * NN;  // 128
    float* lsum   = beff + 128;      // 512
    float* cnt    = lsum + 512;      // 4
    float* lmean  = cnt + 4;         // 512
    float* lmw    = lmean + 512;     // 512
    unsigned short* U    = (unsigned short*)(lmw + 512);  // NH
    unsigned short* V    = U + NH;                        // NH
    unsigned short* WhT  = V + NH;                        // 16384
    unsigned short* WUT  = WhT + 16384;
    unsigned short* WVT  = WUT + 16384;
    unsigned short* WET  = WVT + 16384;                   // 8192
    unsigned short* twhi = WET + 8192;                    // 11*16384
    unsigned short* twlo = twhi + 11 * 16384;             // 11*16384
    unsigned short* hbf  = (unsigned short*)emb1;
    float* hfa = agg;
    float* out = (float*)d_out;

    WSrc ps;
    ps.s[0] = oW;               // oW t0
    ps.s[1] = oW + 16384;       // oW t1
    ps.s[2] = eW1;              // eW1 t0
    ps.s[3] = eW1 + 16384;      // eW1 t1
    ps.s[4] = eoW;
    ps.s[5] = hpW;              // hpW l0..l3
    ps.s[6] = hpW + 16384;
    ps.s[7] = hpW + 2 * 16384;
    ps.s[8] = hpW + 3 * 16384;
    ps.s[9] = hW1;              // hW1a (rows 0..127)
    ps.s[10] = hoW;

    k_prep_tail<<<11 * 64, 256, 0, stream>>>(ps, twhi, twlo);
    k_zero<<<2, 256, 0, stream>>>(lsum, (size_t)516);

    for (int t = 0; t < 2; t++) {
        k_prep_head<<<128, 128, 0, stream>>>(nlW + (size_t)t * 16384, nlb + t * 128,
                                             aW1 + (size_t)t * 384 * 128, ab1 + t * 128,
                                             neW + (size_t)t * 64 * 128, neb + t * 128,
                                             WhT, WUT, WVT, WET, beff);
        k_head<<<NN / 16, 256, 0, stream>>>(nf, WhT, WUT, WVT, nlb + t * 128, hbf, U, V);
        k_zero<<<256, 256, 0, stream>>>(z, (size_t)NN);
        const int* eis = ei + (size_t)t * 2 * EE;
        const int* eid = eis + EE;
        k_edge2<<<(EE + 63) / 64, 256, 0, stream>>>(ef + (size_t)t * EE * 64, eis, eid,
                                                    WET, U, V, beff, aW2 + t * 128,
                                                    ab2 + t, ebuf, z);
        k_zero<<<2048, 256, 0, stream>>>(agg, NH);
        k_agg2<<<EE / 2, 256, 0, stream>>>(hbf, ebuf, eis, eid, agg);
        float* embt = (t == 0) ? emb0 : emb1;
        k_tailA<<<NN / 16, 256, 0, stream>>>(agg, z,
                                             twhi + (size_t)t * 16384, twlo + (size_t)t * 16384,
                                             ob + t * 128, lng + t * 128, lnb + t * 128,
                                             twhi + (size_t)(2 + t) * 16384,
                                             twlo + (size_t)(2 + t) * 16384,
                                             eb1 + t * 128, eW2 + t * 128, eb2 + t,
                                             embt, scores, t);
    }
    k_tailB<<<NN / 16, 256, 0, stream>>>(emb0, emb1, scores, lev,
                                         twhi + (size_t)4 * 16384, twlo + (size_t)4 * 16384,
                                         eob, elg, elb,
                                         twhi + (size_t)5 * 16384, twlo + (size_t)5 * 16384,
                                         hpb,
                                         twhi + (size_t)9 * 16384, twlo + (size_t)9 * 16384,
                                         hfa, lsum, cnt);
    k_lmean_fin<<<4, 128, 0, stream>>>(lsum, cnt, hW1 + 16384, hb1, lmean, lmw);
    k_tailD<<<NN / 16, 256, 0, stream>>>(hfa, lmw, lmean, hW2, hb2,
                                         twhi + (size_t)10 * 16384, twlo + (size_t)10 * 16384,
                                         hob, hlg, hlb, out);
}